// Round 1
// 78.925 us; speedup vs baseline: 1.0007x; 1.0007x over previous
//
#include <hip/hip_runtime.h>

// Problem constants (fixed by setup_inputs): depth (16,1,512,512) fp32, W (8,8) fp32.
// Output (16,3,512,512) fp32.
//
// Math reduction: out[b,c,h,w] = sign(depth[b,0,h,w]) * W[0,1+c] / ||W[0,1:4]||
// (0 where depth==0). Euler scan factor and spectral norm cancel in the final
// normalization. Pure bandwidth kernel: 16.8MB read + 50.3MB write (~10.8us at
// the 6.2 TB/s ceiling measured on this chip's fill dispatches).
//
// This revision vs previous (78.98us bench):
//  - NONTEMPORAL output stores: out is write-only; nt stores avoid displacing
//    the 16.8MB depth input from L2/L3, so replays re-read depth from cache.
//  - 2 float4 groups per thread via split-stride (g and g+HALF): each load and
//    store instruction remains perfectly coalesced (16B/lane contiguous), but
//    per-thread launch/address overhead is halved and the grid becomes
//    2048 blocks = 8 blocks/CU = exactly 32 waves/CU.

typedef float f32x4 __attribute__((ext_vector_type(4)));

constexpr int HW    = 512 * 512;     // 262144 = 2^18
constexpr int BATCH = 16;
constexpr int NPIX  = BATCH * HW;    // 4,194,304
constexpr int NGRP  = NPIX / 4;      // 1,048,576 float4 groups
constexpr int HALF  = NGRP / 2;      // 524,288 threads

__global__ __launch_bounds__(256)
void scene_normal_kernel(const float* __restrict__ depth,
                         const float* __restrict__ Wm,
                         float* __restrict__ out)
{
    // W row-major 8x8: row 0, cols 1..3
    const float w0 = Wm[1], w1 = Wm[2], w2 = Wm[3];
    const float inv = rsqrtf(w0 * w0 + w1 * w1 + w2 * w2);
    const float n0 = w0 * inv, n1 = w1 * inv, n2 = w2 * inv;

    const int t = blockIdx.x * blockDim.x + threadIdx.x;
    if (t >= HALF) return;

#pragma unroll
    for (int half = 0; half < 2; ++half) {
        const int g = t + half * HALF;   // float4-group index, both halves coalesced
        const int p = g * 4;             // pixel index

        // Cached (normal) load: depth stays L3-resident across graph replays.
        const f32x4 x4 = *reinterpret_cast<const f32x4*>(depth + p);

        f32x4 s;
#pragma unroll
        for (int i = 0; i < 4; ++i)
            s[i] = (x4[i] > 0.0f) ? 1.0f : ((x4[i] < 0.0f) ? -1.0f : 0.0f);

        const int b = p >> 18;           // p / HW  (HW = 2^18)
        const int q = p & (HW - 1);      // p % HW  (multiple of 4)
        float* obase = out + (size_t)b * 3 * HW + q;

        // Write-only output: nontemporal stores, don't pollute L2/L3.
        __builtin_nontemporal_store(s * n0, reinterpret_cast<f32x4*>(obase));
        __builtin_nontemporal_store(s * n1, reinterpret_cast<f32x4*>(obase + HW));
        __builtin_nontemporal_store(s * n2, reinterpret_cast<f32x4*>(obase + 2 * HW));
    }
}

extern "C" void kernel_launch(void* const* d_in, const int* in_sizes, int n_in,
                              void* d_out, int out_size, void* d_ws, size_t ws_size,
                              hipStream_t stream)
{
    const float* depth = (const float*)d_in[0];  // 16*1*512*512 fp32
    const float* Wm    = (const float*)d_in[1];  // 8*8 fp32
    float* out = (float*)d_out;                  // 16*3*512*512 fp32

    const int block = 256;
    const int grid  = HALF / block;              // 2048 blocks, exact
    scene_normal_kernel<<<grid, block, 0, stream>>>(depth, Wm, out);
}